// Round 7
// baseline (2596.402 us; speedup 1.0000x reference)
//
#include <hip/hip_runtime.h>
#include <cstdint>
#include <cstddef>

#define S 108
#define NEMIT 126
#define NCOD 16
#define T_LEN 2048
#define N_BATCH 256
#define MAXG 12    // max gather entries per lane after balancing
#define MAXNE 6500 // emission nnz upper bound (actual 6432)

// ================= compile-time emission structure =================
struct EmTab {
  short row[MAXNE];
  short col[MAXNE];
  short widx[MAXNE];
  int rp[S + 1];
  int n;
  int nw;
};

constexpr int cmask(int sym, int add4) {
  int m = (sym == 4) ? 0xF : (1 << sym);
  if (add4) m |= 0x10;
  return m;
}

constexpr EmTab buildEm() {
  EmTab E{};
  int n = 0, k = 0;
  auto doCall = [&](int stt, int s0_, int s1_, int s2_, int xm_, int tr_) {
    const int m0 = cmask(s0_, xm_ < 2 ? 1 : 0);
    const int m1 = cmask(s1_, xm_ < 1 ? 1 : 0);
    const int m2 = cmask(s2_, 0);
    for (int x0 = 0; x0 < 5; x0++) {
      if (!((m0 >> x0) & 1)) continue;
      for (int x1 = 0; x1 < 5; x1++) {
        if (!((m1 >> x1) & 1)) continue;
        if (x0 != 4 && x1 == 4) continue;
        for (int x2 = 0; x2 < 5; x2++) {
          if (!((m2 >> x2) & 1)) continue;
          E.row[n] = (short)stt;
          E.col[n] = (short)(x0 * 25 + x1 * 5 + x2);
          E.widx[n] = (short)(tr_ ? k++ : -1);
          n++;
        }
      }
    }
  };
  doCall(0, 4, 4, 4, 0, 1);
  doCall(1, 4, 4, 0, 0, 1);
  doCall(2, 4, 0, 3, 0, 1);
  doCall(3, 0, 3, 2, 2, 0);
  doCall(4, 3, 2, 4, 2, 1);
  doCall(5, 2, 4, 4, 2, 1);
  for (int s = 6; s <= 51; s++) doCall(s, 4, 4, 4, 2, 1);
  doCall(52, 4, 4, 3, 2, 1);
  doCall(53, 4, 3, 0, 2, 1);
  doCall(53, 4, 3, 2, 2, 1);
  doCall(54, 3, 0, 0, 2, 0);
  doCall(54, 3, 0, 2, 2, 0);
  doCall(54, 3, 2, 0, 2, 0);
  doCall(55, 4, 4, 4, 2, 1);
  for (int s = 56; s <= 106; s++) doCall(s, 4, 4, 4, 2, 1);
  E.row[n] = 107; E.col[n] = 125; E.widx[n] = -1; n++;
  E.n = n; E.nw = k;
  for (int r = 0; r <= S; r++) E.rp[r] = 0;
  for (int e = 0; e < n; e++) E.rp[E.row[e] + 1]++;
  for (int r = 0; r < S; r++) E.rp[r + 1] += E.rp[r];
  return E;
}

constexpr EmTab EM_HOST = buildEm();
static_assert(EM_HOST.n <= MAXNE && EM_HOST.n > 6000, "emission count sanity");
__device__ const EmTab g_em = EM_HOST;

// ================= PROBE 1: bare loop-carried gather core (2047 steps) ========
// 12 gathers + 2 bt reads + FMA tree + 2 alpha writes. Nothing else.
__global__ __launch_bounds__(64, 1) void probe_core(const float* __restrict__ ik,
                                                    float* __restrict__ ws, int wn) {
  __shared__ float alpha[128];
  __shared__ float btl[128];
  const int tid = threadIdx.x;
  alpha[tid] = 0.5f + 0.001f * tid + 1e-6f * ik[tid & 63];
  alpha[tid + 64] = 0.25f + 1e-6f * ik[tid & 31];
  btl[tid] = 0.95f + 1e-7f * tid;
  btl[tid + 64] = 0.93f + 1e-7f * tid;
  __syncthreads();
  int gsrc[MAXG]; float w0v[MAXG], w1v[MAXG];
#pragma unroll
  for (int e = 0; e < MAXG; e++) {
    gsrc[e] = (tid * 7 + e * 13) % 108;
    w0v[e] = 0.088f + 0.0001f * e;
    w1v[e] = 0.086f + 0.0001f * e;
  }
  const int d0 = tid, d1 = 64 + tid;
  float u0 = 0.f, u1 = 0.f;
  for (int t = 1; t < T_LEN; t++) {
    const float bt0 = btl[(t * 37 + tid) & 127];
    const float bt1 = btl[(t * 53 + tid) & 127];
    float x[MAXG];
#pragma unroll
    for (int e = 0; e < MAXG; e++) x[e] = alpha[gsrc[e]];
    float aA = 0.f, aB = 0.f, bA = 0.f, bB = 0.f;
#pragma unroll
    for (int e = 0; e < MAXG; e += 2) {
      aA += x[e] * w0v[e];     aB += x[e + 1] * w0v[e + 1];
      bA += x[e] * w1v[e];     bB += x[e + 1] * w1v[e + 1];
    }
    u0 = (aA + aB) * bt0;
    u1 = (bA + bB) * bt1;
    alpha[d0] = u0;
    alpha[d1] = u1;
  }
  const int widx = (int)(blockIdx.x * 64u + tid);
  if (widx < wn) ws[widx] = u0 + u1;
}

// ================= PROBE 2: full replica of R5 loop (3x2047 steps) ============
// Same gather core + real uniform seq loads from inp + full-size Bt LDS reads +
// real-pattern exec-masked scattered stores into OUT (overwritten by the real
// kernel afterwards) + the every-16 max-shuffle rescale.
__global__ __launch_bounds__(64, 1) void probe_full(const int* __restrict__ inp,
                                                    const float* __restrict__ ik,
                                                    float* __restrict__ out) {
  __shared__ __align__(16) float Btp[NEMIT * S];
  __shared__ float alpha[128];
  const int tid = threadIdx.x;
  for (int i = tid; i < NEMIT * S; i += 64) Btp[i] = 0.9f + 1e-7f * (float)(i & 1023);
  alpha[tid] = 0.5f + 0.001f * tid + 1e-6f * ik[tid & 63];
  alpha[tid + 64] = 0.25f + 1e-6f * ik[tid & 31];
  __syncthreads();
  int gsrc[MAXG]; float w0v[MAXG], w1v[MAXG];
#pragma unroll
  for (int e = 0; e < MAXG; e++) {
    gsrc[e] = (tid * 7 + e * 13) % 108;
    w0v[e] = 0.088f + 0.0001f * e;
    w1v[e] = 0.086f + 0.0001f * e;
  }
  const int d0 = tid, d1 = 64 + tid;
  const int b0c = tid, b1c = (tid + 54) % 108;
  const int* seq = inp + (size_t)blockIdx.x * T_LEN;
  float* ob = out + (size_t)blockIdx.x * T_LEN * S;
  float u0 = 0.f, u1 = 0.f;
  int etn = seq[1];
  for (int t = 1; t < 3 * (T_LEN - 1) + 1; t++) {
    const int t2 = 1 + ((t - 1) % (T_LEN - 1));       // 1..2047
    const int ecur = etn;
    etn = seq[(t2 + 1 < T_LEN) ? t2 + 1 : 1];          // uniform prefetch like R5
    const float bt0 = Btp[ecur * S + b0c];
    const float bt1 = Btp[ecur * S + b1c];
    float x[MAXG];
#pragma unroll
    for (int e = 0; e < MAXG; e++) x[e] = alpha[gsrc[e]];
    float aA = 0.f, aB = 0.f, bA = 0.f, bB = 0.f;
#pragma unroll
    for (int e = 0; e < MAXG; e += 2) {
      aA += x[e] * w0v[e];     aB += x[e + 1] * w0v[e + 1];
      bA += x[e] * w1v[e];     bB += x[e + 1] * w1v[e + 1];
    }
    u0 = (aA + aB) * bt0;
    u1 = (bA + bB) * bt1;
    const float sumv = x[0] + x[1] + x[2];

    if ((t & 15) == 15) {
      float m = fmaxf(u0, u1);
#pragma unroll
      for (int msk = 1; msk < 64; msk <<= 1) m = fmaxf(m, __shfl_xor(m, msk, 64));
      const float r = 1.f / m;
      u0 *= r; u1 *= r;
    }

    alpha[d0] = u0;
    alpha[d1] = u1;
    // real-pattern exec-masked scattered stores (garbage; overwritten later)
    if (tid < 54) ob[(size_t)t2 * S + tid] = u0;
    if (tid >= 20) ob[(size_t)t2 * S + (44 + tid)] = u1;
    if (tid >= 54) ob[(size_t)(t2 - 1) * S + (tid * 2) % 108] = sumv;
  }
}

// ================= scan kernel (EXACT R5 — unchanged) =================
__global__ __launch_bounds__(64, 1) void hmm_scan_kernel(
    const int* __restrict__ inp, const float* __restrict__ w,
    const float* __restrict__ ek, const float* __restrict__ ik,
    float* __restrict__ out) {
  __shared__ __align__(16) float Bt_lds[NEMIT * S];
  __shared__ float alpha_lds[128];     // 108 states + 14 piece pads + trash(127)
  __shared__ float pi_lds[S];
  __shared__ short arow[280], acol[280];
  __shared__ float avalS[280];
  __shared__ int s_ne;
  // planner state
  __shared__ short ccnt[S];
  __shared__ short clist[S][18];
  __shared__ short npcA[S];
  __shared__ short pdefs[16][6];
  __shared__ short pcnt_s[16], pcol_s[16];
  // per-lane plan
  __shared__ unsigned char p_src[64][MAXG];
  __shared__ short p_a0[64][MAXG], p_a1[64][MAXG];
  __shared__ unsigned char p_dslot[64][2], p_btc[64][2];
  __shared__ short p_outc[64][2];
  __shared__ short p_scol[64];
  __shared__ unsigned char p_sm1[64], p_sm2[64];
  __shared__ unsigned char lload[64], lnit[64];

  const int tid = threadIdx.x;   // 64 threads = 1 wave

  // ---------- phase 0: zero Bt; plan defaults; pi softmax; A entries ----------
  for (int i = tid; i < NEMIT * S; i += 64) Bt_lds[i] = 0.f;
#pragma unroll
  for (int e = 0; e < MAXG; e++) {
    p_src[tid][e] = 0; p_a0[tid][e] = -1; p_a1[tid][e] = -1;
  }
  p_dslot[tid][0] = 127; p_dslot[tid][1] = 127;
  p_btc[tid][0] = 0; p_btc[tid][1] = 0;
  p_outc[tid][0] = -1; p_outc[tid][1] = -1;
  p_scol[tid] = -1; p_sm1[tid] = 0; p_sm2[tid] = 0;
  lload[tid] = 0; lnit[tid] = 0;

  {  // pi = softmax(ik)
    float q0 = (tid < S) ? ik[tid] : -1e30f;
    float q1 = (tid + 64 < S) ? ik[tid + 64] : -1e30f;
    float mx = fmaxf(q0, q1);
#pragma unroll
    for (int msk = 1; msk < 64; msk <<= 1) mx = fmaxf(mx, __shfl_xor(mx, msk, 64));
    float e0v = (tid < S) ? expf(q0 - mx) : 0.f;
    float e1v = (tid + 64 < S) ? expf(q1 - mx) : 0.f;
    float zz = e0v + e1v;
#pragma unroll
    for (int msk = 1; msk < 64; msk <<= 1) zz += __shfl_xor(zz, msk, 64);
    const float rz = 1.f / zz;
    if (tid < S) pi_lds[tid] = e0v * rz;
    if (tid + 64 < S) pi_lds[tid + 64] = e1v * rz;
  }

  if (tid == 1) {
    // _build_A(w, 16): 280 entries
    int ne = 0;
    auto AD = [&](int r, int c2, float v) {
      arow[ne] = (short)r; acol[ne] = (short)c2; avalS[ne] = v; ne++;
    };
    float w0 = w[0];
    AD(0, 0, 1.f - w0); AD(0, 1, w0); AD(1, 2, 1.f); AD(2, 3, 1.f);
    int k = 1;
    for (int i = 0; i < NCOD; i++) AD(3 + 3 * i, 4 + 3 * i, w[k + i]);
    k += NCOD;
    for (int i = 0; i < NCOD; i++) AD(4 + 3 * i, 5 + 3 * i, 1.f);
    for (int i = 0; i < NCOD; i++) AD(5 + 3 * i, 6 + 3 * i, 1.f);
    for (int i = 0; i <= NCOD; i++) AD(3 + 3 * i, 56 + 3 * i, w[k + i]);
    k += NCOD + 1;
    AD(51, 52, w[k]); k += 1;
    for (int i = 0; i <= NCOD; i++) AD(56 + 3 * i, 57 + 3 * i, 1.f);
    for (int i = 0; i <= NCOD; i++) AD(57 + 3 * i, 58 + 3 * i, 1.f);
    for (int i = 0; i <= NCOD; i++) AD(58 + 3 * i, 4 + 3 * i, w[k + i]);
    for (int i = 0; i <= NCOD; i++) AD(58 + 3 * i, 56 + 3 * i, 1.f - w[k + i]);
    k += NCOD + 1;
    const float wk = w[k];
    const float sgnw = (wk > 0.f) ? 1.f : ((wk < 0.f) ? -1.f : 0.f);
    const float aw = fabsf(wk);
    for (int a = 0; a < NCOD; a++) {
      float pw = aw * aw;
      int e = 2;
      for (int jj = a + 1; jj <= NCOD; jj++) {
        const float sgn = (e & 1) ? sgnw : 1.f;
        AD(3 + 3 * a, 4 + 3 * jj, 1.f - sgn * pw);
        pw *= aw; e++;
      }
    }
    AD(52, 53, 1.f); AD(53, 54, 1.f); AD(54, 55, 1.f);
    AD(55, 55, 1.f); AD(55, 107, 1.f); AD(107, 107, 1.f);
    s_ne = ne;    // = 280
  }
  __syncthreads();

  const int ne = s_ne;

  // ---------- phase 1: A row-softmax (parallel) + per-col source lists ----------
  for (int s = tid; s < S; s += 64) {
    float m = -1e30f;
    for (int e = 0; e < ne; e++)
      if (arow[e] == s) m = fmaxf(m, avalS[e]);
    float z = 0.f;
    for (int e = 0; e < ne; e++)
      if (arow[e] == s) z += expf(avalS[e] - m);
    const float rz = 1.f / z;
    for (int e = 0; e < ne; e++)
      if (arow[e] == s) avalS[e] = expf(avalS[e] - m) * rz;
  }
  for (int c = tid; c < S; c += 64) {
    int cnt = 0;
    for (int e = 0; e < ne; e++)
      if (acol[e] == c) { clist[c][cnt] = (short)e; cnt++; }
    ccnt[c] = (short)cnt;
  }
  __syncthreads();

  // ---------- phase 2: B row-softmax (parallel) + planner (lane 0) ----------
#pragma unroll
  for (int rr2 = 0; rr2 < 2; rr2++) {
    const int r = tid + rr2 * 64;
    if (r < S) {
      const int b = g_em.rp[r], e2 = g_em.rp[r + 1];
      float m = -1e30f;
      for (int e = b; e < e2; e++) {
        const int wi = g_em.widx[e];
        m = fmaxf(m, (wi >= 0) ? ek[wi] : 1.f);
      }
      float z = 0.f;
      for (int e = b; e < e2; e++) {
        const int wi = g_em.widx[e];
        z += expf(((wi >= 0) ? ek[wi] : 1.f) - m);
      }
      const float rz = 1.f / z;
      for (int e = b; e < e2; e++) {
        const int wi = g_em.widx[e];
        Bt_lds[(int)g_em.col[e] * S + r] = expf(((wi >= 0) ? ek[wi] : 1.f) - m) * rz;
      }
    }
  }

  if (tid == 0) {
    // --- decomposition: carve heavy columns into pieces of 6 sources ---
    int np = 0;
    for (int c = 0; c < S; c++) npcA[c] = 0;
    for (int c = 0; c < S; c++) {
      while (ccnt[c] > 8) {
        const int base = ccnt[c] - 6;
        for (int j = 0; j < 6; j++) pdefs[np][j] = clist[c][base + j];
        pcnt_s[np] = 6; pcol_s[np] = (short)c;
        npcA[c]++; ccnt[c] = (short)(ccnt[c] - 6); np++;
      }
    }
    // --- consumers (unique readers of split cols) -> lanes 54..63, item0 ---
    int ncons = 0;
    for (int c = 0; c < S; c++) {
      if (ccnt[c] == 1) {
        const int e0 = clist[c][0];
        const int r = arow[e0];
        if (npcA[r] > 0) {
          const int l = 54 + ncons; ncons++;
          int k = 0;
          p_src[l][k] = (unsigned char)r; p_a0[l][k] = (short)e0; k++;
          for (int p = 0; p < np; p++)
            if (pcol_s[p] == r) {
              p_src[l][k] = (unsigned char)(108 + p); p_a0[l][k] = (short)e0; k++;
            }
          p_dslot[l][0] = (unsigned char)c; p_btc[l][0] = (unsigned char)c;
          p_outc[l][0] = (short)c;
          p_scol[l] = (short)r;
          p_sm1[l] = (k >= 2) ? 1 : 0; p_sm2[l] = (k >= 3) ? 1 : 0;
          lload[l] = (unsigned char)k; lnit[l] = 1;
          ccnt[c] = 0;   // consumed
        }
      }
    }
    // --- snake-deal remaining items (pieces + real cols), big first ---
    int rr = 0;
    auto pickLane = [&](int L) {
      for (;;) {
        const int pos = rr & 127; rr++;
        const int l = (pos < 64) ? pos : (127 - pos);
        if (lnit[l] < 2 && (int)lload[l] + L <= MAXG) return l;
      }
    };
    for (int th = 8; th >= 1; th--) {
      for (int p = 0; p < np; p++) {
        if ((int)pcnt_s[p] != th) continue;
        const int l = pickLane(th);
        const int it = lnit[l]; const int base = lload[l];
        for (int j = 0; j < th; j++) {
          p_src[l][base + j] = (unsigned char)arow[pdefs[p][j]];
          if (it == 0) p_a0[l][base + j] = pdefs[p][j];
          else         p_a1[l][base + j] = pdefs[p][j];
        }
        p_dslot[l][it] = (unsigned char)(108 + p);
        p_btc[l][it] = (unsigned char)pcol_s[p];
        p_outc[l][it] = -1;
        lload[l] = (unsigned char)(base + th); lnit[l] = (unsigned char)(it + 1);
      }
      for (int c = 0; c < S; c++) {
        if ((int)ccnt[c] != th) continue;
        const int l = pickLane(th);
        const int it = lnit[l]; const int base = lload[l];
        for (int j = 0; j < th; j++) {
          p_src[l][base + j] = (unsigned char)arow[clist[c][j]];
          if (it == 0) p_a0[l][base + j] = clist[c][j];
          else         p_a1[l][base + j] = clist[c][j];
        }
        p_dslot[l][it] = (unsigned char)c;
        p_btc[l][it] = (unsigned char)c;
        p_outc[l][it] = (npcA[c] > 0) ? (short)-1 : (short)c;
        lload[l] = (unsigned char)(base + th); lnit[l] = (unsigned char)(it + 1);
      }
    }
  }
  __syncthreads();

  // ---------- phase 3: load per-lane plan into registers ----------
  int gsrc[MAXG]; float w0v[MAXG], w1v[MAXG];
#pragma unroll
  for (int e = 0; e < MAXG; e++) {
    gsrc[e] = p_src[tid][e];
    const int a0 = p_a0[tid][e], a1 = p_a1[tid][e];
    w0v[e] = (a0 >= 0) ? avalS[a0] : 0.f;
    w1v[e] = (a1 >= 0) ? avalS[a1] : 0.f;
  }
  const int d0 = p_dslot[tid][0], d1 = p_dslot[tid][1];
  const int b0c = p_btc[tid][0], b1c = p_btc[tid][1];
  const int o0 = p_outc[tid][0], o1 = p_outc[tid][1];
  const int scol = p_scol[tid];
  const float sm1 = (float)p_sm1[tid], sm2 = (float)p_sm2[tid];
  __syncthreads();

  // ---------- phase 4: forward scan (unnormalized), no in-loop cross-lane ------
  const int* seq = inp + (size_t)blockIdx.x * T_LEN;
  float* ob = out + (size_t)blockIdx.x * T_LEN * S;

  const int e0s = seq[0];
  {
    const float ui0 = (d0 < 108) ? pi_lds[d0] * Bt_lds[e0s * S + d0] : 0.f;
    const float ui1 = (d1 < 108) ? pi_lds[d1] * Bt_lds[e0s * S + d1] : 0.f;
    alpha_lds[d0] = ui0;
    alpha_lds[d1] = ui1;
  }
  __syncthreads();
  for (int i = tid; i < S; i += 64) ob[i] = alpha_lds[i];   // row 0 (unnormalized)

  int etn = seq[1];
  for (int t = 1; t < T_LEN; t++) {
    const int ecur = etn;
    if (t + 1 < T_LEN) etn = seq[t + 1];
    const float bt0 = Bt_lds[ecur * S + b0c];   // issue early, overlaps gathers
    const float bt1 = Bt_lds[ecur * S + b1c];
    float x[MAXG];
#pragma unroll
    for (int e = 0; e < MAXG; e++) x[e] = alpha_lds[gsrc[e]];
    float aA = 0.f, aB = 0.f, bA = 0.f, bB = 0.f;
#pragma unroll
    for (int e = 0; e < MAXG; e += 2) {
      aA += x[e] * w0v[e];     aB += x[e + 1] * w0v[e + 1];
      bA += x[e] * w1v[e];     bB += x[e + 1] * w1v[e + 1];
    }
    float u0 = (aA + aB) * bt0;
    float u1 = (bA + bB) * bt1;
    const float sumv = x[0] + sm1 * x[1] + sm2 * x[2];   // full split-col value (row t-1)

    if ((t & 15) == 15) {                  // periodic wave-uniform rescale
      float m = fmaxf(u0, u1);
#pragma unroll
      for (int msk = 1; msk < 64; msk <<= 1) m = fmaxf(m, __shfl_xor(m, msk, 64));
      const float r = 1.f / m;
      u0 *= r; u1 *= r;
    }

    alpha_lds[d0] = u0;
    alpha_lds[d1] = u1;
    if (o0 >= 0) ob[(size_t)t * S + o0] = u0;
    if (o1 >= 0) ob[(size_t)t * S + o1] = u1;
    if (scol >= 0) ob[(size_t)(t - 1) * S + scol] = sumv;
  }
  // epilogue: last row's split-col values
  if (scol >= 0) {
    const float x0 = alpha_lds[gsrc[0]];
    const float x1 = alpha_lds[gsrc[1]];
    const float x2 = alpha_lds[gsrc[2]];
    ob[(size_t)(T_LEN - 1) * S + scol] = x0 + sm1 * x1 + sm2 * x2;
  }
}

// ---------- kernel: per-row normalization, fully parallel, BW-bound ----------
__global__ __launch_bounds__(256, 8) void hmm_norm_kernel(float* __restrict__ out,
                                                          int nrows) {
  const int wid = (int)((blockIdx.x * 256u + threadIdx.x) >> 6);  // one wave per row
  const int l = threadIdx.x & 63;
  if (wid >= nrows) return;
  float* row = out + (size_t)wid * S;
  float2 x = make_float2(0.f, 0.f);
  if (l < 54) x = *(const float2*)&row[2 * l];
  float s = x.x + x.y;
#pragma unroll
  for (int msk = 1; msk < 64; msk <<= 1) s += __shfl_xor(s, msk, 64);
  const float inv = 1.f / s;
  if (l < 54) *(float2*)&row[2 * l] = make_float2(x.x * inv, x.y * inv);
}

extern "C" void kernel_launch(void* const* d_in, const int* in_sizes, int n_in,
                              void* d_out, int out_size, void* d_ws, size_t ws_size,
                              hipStream_t stream) {
  const int* inp = (const int*)d_in[0];
  const float* w = (const float*)d_in[1];
  const float* ek = (const float*)d_in[2];
  const float* ik = (const float*)d_in[3];
  float* out = (float*)d_out;
  float* ws = (float*)d_ws;
  const int wn = (int)(ws_size / 4);
  // Probes FIRST: probe_full writes garbage into out, fully overwritten by the
  // real scan + norm kernels below. probe_core writes only into d_ws.
  probe_full<<<N_BATCH, 64, 0, stream>>>(inp, ik, out);
  probe_core<<<N_BATCH, 64, 0, stream>>>(ik, ws, wn);
  hmm_scan_kernel<<<N_BATCH, 64, 0, stream>>>(inp, w, ek, ik, out);
  const int nrows = N_BATCH * T_LEN;
  hmm_norm_kernel<<<nrows / 4, 256, 0, stream>>>(out, nrows);
}

// Round 8
// 936.794 us; speedup vs baseline: 2.7716x; 2.7716x over previous
//
#include <hip/hip_runtime.h>
#include <cstdint>
#include <cstddef>

#define S 108
#define NEMIT 126
#define NCOD 16
#define T_LEN 2048
#define N_BATCH 256
#define MAXG 12    // max gather entries per lane after balancing
#define MAXNE 6500 // emission nnz upper bound (actual 6432)

// Value-range management (anti-denormal):
//  - alpha is kept scaled so the wave max is 1e24 after each every-16 rescale.
//  - any state value below 1e-30 is flushed to exact 0 each step, so nothing
//    in alpha_lds (or any product x*w >= 1e-30*5e-3 = 5e-33) is ever denormal.
#define RESCALE_TARGET 1e24f
#define FLUSH_EPS 1e-30f

// ================= compile-time emission structure =================
struct EmTab {
  short row[MAXNE];
  short col[MAXNE];
  short widx[MAXNE];
  int rp[S + 1];
  int n;
  int nw;
};

constexpr int cmask(int sym, int add4) {
  int m = (sym == 4) ? 0xF : (1 << sym);
  if (add4) m |= 0x10;
  return m;
}

constexpr EmTab buildEm() {
  EmTab E{};
  int n = 0, k = 0;
  auto doCall = [&](int stt, int s0_, int s1_, int s2_, int xm_, int tr_) {
    const int m0 = cmask(s0_, xm_ < 2 ? 1 : 0);
    const int m1 = cmask(s1_, xm_ < 1 ? 1 : 0);
    const int m2 = cmask(s2_, 0);
    for (int x0 = 0; x0 < 5; x0++) {
      if (!((m0 >> x0) & 1)) continue;
      for (int x1 = 0; x1 < 5; x1++) {
        if (!((m1 >> x1) & 1)) continue;
        if (x0 != 4 && x1 == 4) continue;
        for (int x2 = 0; x2 < 5; x2++) {
          if (!((m2 >> x2) & 1)) continue;
          E.row[n] = (short)stt;
          E.col[n] = (short)(x0 * 25 + x1 * 5 + x2);
          E.widx[n] = (short)(tr_ ? k++ : -1);
          n++;
        }
      }
    }
  };
  doCall(0, 4, 4, 4, 0, 1);
  doCall(1, 4, 4, 0, 0, 1);
  doCall(2, 4, 0, 3, 0, 1);
  doCall(3, 0, 3, 2, 2, 0);
  doCall(4, 3, 2, 4, 2, 1);
  doCall(5, 2, 4, 4, 2, 1);
  for (int s = 6; s <= 51; s++) doCall(s, 4, 4, 4, 2, 1);
  doCall(52, 4, 4, 3, 2, 1);
  doCall(53, 4, 3, 0, 2, 1);
  doCall(53, 4, 3, 2, 2, 1);
  doCall(54, 3, 0, 0, 2, 0);
  doCall(54, 3, 0, 2, 2, 0);
  doCall(54, 3, 2, 0, 2, 0);
  doCall(55, 4, 4, 4, 2, 1);
  for (int s = 56; s <= 106; s++) doCall(s, 4, 4, 4, 2, 1);
  E.row[n] = 107; E.col[n] = 125; E.widx[n] = -1; n++;
  E.n = n; E.nw = k;
  for (int r = 0; r <= S; r++) E.rp[r] = 0;
  for (int e = 0; e < n; e++) E.rp[E.row[e] + 1]++;
  for (int r = 0; r < S; r++) E.rp[r + 1] += E.rp[r];
  return E;
}

constexpr EmTab EM_HOST = buildEm();
static_assert(EM_HOST.n <= MAXNE && EM_HOST.n > 6000, "emission count sanity");
__device__ const EmTab g_em = EM_HOST;

// ================= scan kernel (R5 + anti-denormal value management) ==========
__global__ __launch_bounds__(64, 1) void hmm_scan_kernel(
    const int* __restrict__ inp, const float* __restrict__ w,
    const float* __restrict__ ek, const float* __restrict__ ik,
    float* __restrict__ out) {
  __shared__ __align__(16) float Bt_lds[NEMIT * S];
  __shared__ float alpha_lds[128];     // 108 states + 14 piece pads + trash(127)
  __shared__ float pi_lds[S];
  __shared__ short arow[280], acol[280];
  __shared__ float avalS[280];
  __shared__ int s_ne;
  // planner state
  __shared__ short ccnt[S];
  __shared__ short clist[S][18];
  __shared__ short npcA[S];
  __shared__ short pdefs[16][6];
  __shared__ short pcnt_s[16], pcol_s[16];
  // per-lane plan
  __shared__ unsigned char p_src[64][MAXG];
  __shared__ short p_a0[64][MAXG], p_a1[64][MAXG];
  __shared__ unsigned char p_dslot[64][2], p_btc[64][2];
  __shared__ short p_outc[64][2];
  __shared__ short p_scol[64];
  __shared__ unsigned char p_sm1[64], p_sm2[64];
  __shared__ unsigned char lload[64], lnit[64];

  const int tid = threadIdx.x;   // 64 threads = 1 wave

  // ---------- phase 0: zero Bt; plan defaults; pi softmax; A entries ----------
  for (int i = tid; i < NEMIT * S; i += 64) Bt_lds[i] = 0.f;
#pragma unroll
  for (int e = 0; e < MAXG; e++) {
    p_src[tid][e] = 0; p_a0[tid][e] = -1; p_a1[tid][e] = -1;
  }
  p_dslot[tid][0] = 127; p_dslot[tid][1] = 127;
  p_btc[tid][0] = 0; p_btc[tid][1] = 0;
  p_outc[tid][0] = -1; p_outc[tid][1] = -1;
  p_scol[tid] = -1; p_sm1[tid] = 0; p_sm2[tid] = 0;
  lload[tid] = 0; lnit[tid] = 0;

  {  // pi = softmax(ik)
    float q0 = (tid < S) ? ik[tid] : -1e30f;
    float q1 = (tid + 64 < S) ? ik[tid + 64] : -1e30f;
    float mx = fmaxf(q0, q1);
#pragma unroll
    for (int msk = 1; msk < 64; msk <<= 1) mx = fmaxf(mx, __shfl_xor(mx, msk, 64));
    float e0v = (tid < S) ? expf(q0 - mx) : 0.f;
    float e1v = (tid + 64 < S) ? expf(q1 - mx) : 0.f;
    float zz = e0v + e1v;
#pragma unroll
    for (int msk = 1; msk < 64; msk <<= 1) zz += __shfl_xor(zz, msk, 64);
    const float rz = 1.f / zz;
    if (tid < S) pi_lds[tid] = e0v * rz;
    if (tid + 64 < S) pi_lds[tid + 64] = e1v * rz;
  }

  if (tid == 1) {
    // _build_A(w, 16): 280 entries
    int ne = 0;
    auto AD = [&](int r, int c2, float v) {
      arow[ne] = (short)r; acol[ne] = (short)c2; avalS[ne] = v; ne++;
    };
    float w0 = w[0];
    AD(0, 0, 1.f - w0); AD(0, 1, w0); AD(1, 2, 1.f); AD(2, 3, 1.f);
    int k = 1;
    for (int i = 0; i < NCOD; i++) AD(3 + 3 * i, 4 + 3 * i, w[k + i]);
    k += NCOD;
    for (int i = 0; i < NCOD; i++) AD(4 + 3 * i, 5 + 3 * i, 1.f);
    for (int i = 0; i < NCOD; i++) AD(5 + 3 * i, 6 + 3 * i, 1.f);
    for (int i = 0; i <= NCOD; i++) AD(3 + 3 * i, 56 + 3 * i, w[k + i]);
    k += NCOD + 1;
    AD(51, 52, w[k]); k += 1;
    for (int i = 0; i <= NCOD; i++) AD(56 + 3 * i, 57 + 3 * i, 1.f);
    for (int i = 0; i <= NCOD; i++) AD(57 + 3 * i, 58 + 3 * i, 1.f);
    for (int i = 0; i <= NCOD; i++) AD(58 + 3 * i, 4 + 3 * i, w[k + i]);
    for (int i = 0; i <= NCOD; i++) AD(58 + 3 * i, 56 + 3 * i, 1.f - w[k + i]);
    k += NCOD + 1;
    const float wk = w[k];
    const float sgnw = (wk > 0.f) ? 1.f : ((wk < 0.f) ? -1.f : 0.f);
    const float aw = fabsf(wk);
    for (int a = 0; a < NCOD; a++) {
      float pw = aw * aw;
      int e = 2;
      for (int jj = a + 1; jj <= NCOD; jj++) {
        const float sgn = (e & 1) ? sgnw : 1.f;
        AD(3 + 3 * a, 4 + 3 * jj, 1.f - sgn * pw);
        pw *= aw; e++;
      }
    }
    AD(52, 53, 1.f); AD(53, 54, 1.f); AD(54, 55, 1.f);
    AD(55, 55, 1.f); AD(55, 107, 1.f); AD(107, 107, 1.f);
    s_ne = ne;    // = 280
  }
  __syncthreads();

  const int ne = s_ne;

  // ---------- phase 1: A row-softmax (parallel) + per-col source lists ----------
  for (int s = tid; s < S; s += 64) {
    float m = -1e30f;
    for (int e = 0; e < ne; e++)
      if (arow[e] == s) m = fmaxf(m, avalS[e]);
    float z = 0.f;
    for (int e = 0; e < ne; e++)
      if (arow[e] == s) z += expf(avalS[e] - m);
    const float rz = 1.f / z;
    for (int e = 0; e < ne; e++)
      if (arow[e] == s) avalS[e] = expf(avalS[e] - m) * rz;
  }
  for (int c = tid; c < S; c += 64) {
    int cnt = 0;
    for (int e = 0; e < ne; e++)
      if (acol[e] == c) { clist[c][cnt] = (short)e; cnt++; }
    ccnt[c] = (short)cnt;
  }
  __syncthreads();

  // ---------- phase 2: B row-softmax (parallel) + planner (lane 0) ----------
#pragma unroll
  for (int rr2 = 0; rr2 < 2; rr2++) {
    const int r = tid + rr2 * 64;
    if (r < S) {
      const int b = g_em.rp[r], e2 = g_em.rp[r + 1];
      float m = -1e30f;
      for (int e = b; e < e2; e++) {
        const int wi = g_em.widx[e];
        m = fmaxf(m, (wi >= 0) ? ek[wi] : 1.f);
      }
      float z = 0.f;
      for (int e = b; e < e2; e++) {
        const int wi = g_em.widx[e];
        z += expf(((wi >= 0) ? ek[wi] : 1.f) - m);
      }
      const float rz = 1.f / z;
      for (int e = b; e < e2; e++) {
        const int wi = g_em.widx[e];
        Bt_lds[(int)g_em.col[e] * S + r] = expf(((wi >= 0) ? ek[wi] : 1.f) - m) * rz;
      }
    }
  }

  if (tid == 0) {
    // --- decomposition: carve heavy columns into pieces of 6 sources ---
    int np = 0;
    for (int c = 0; c < S; c++) npcA[c] = 0;
    for (int c = 0; c < S; c++) {
      while (ccnt[c] > 8) {
        const int base = ccnt[c] - 6;
        for (int j = 0; j < 6; j++) pdefs[np][j] = clist[c][base + j];
        pcnt_s[np] = 6; pcol_s[np] = (short)c;
        npcA[c]++; ccnt[c] = (short)(ccnt[c] - 6); np++;
      }
    }
    // --- consumers (unique readers of split cols) -> lanes 54..63, item0 ---
    int ncons = 0;
    for (int c = 0; c < S; c++) {
      if (ccnt[c] == 1) {
        const int e0 = clist[c][0];
        const int r = arow[e0];
        if (npcA[r] > 0) {
          const int l = 54 + ncons; ncons++;
          int k = 0;
          p_src[l][k] = (unsigned char)r; p_a0[l][k] = (short)e0; k++;
          for (int p = 0; p < np; p++)
            if (pcol_s[p] == r) {
              p_src[l][k] = (unsigned char)(108 + p); p_a0[l][k] = (short)e0; k++;
            }
          p_dslot[l][0] = (unsigned char)c; p_btc[l][0] = (unsigned char)c;
          p_outc[l][0] = (short)c;
          p_scol[l] = (short)r;
          p_sm1[l] = (k >= 2) ? 1 : 0; p_sm2[l] = (k >= 3) ? 1 : 0;
          lload[l] = (unsigned char)k; lnit[l] = 1;
          ccnt[c] = 0;   // consumed
        }
      }
    }
    // --- snake-deal remaining items (pieces + real cols), big first ---
    int rr = 0;
    auto pickLane = [&](int L) {
      for (;;) {
        const int pos = rr & 127; rr++;
        const int l = (pos < 64) ? pos : (127 - pos);
        if (lnit[l] < 2 && (int)lload[l] + L <= MAXG) return l;
      }
    };
    for (int th = 8; th >= 1; th--) {
      for (int p = 0; p < np; p++) {
        if ((int)pcnt_s[p] != th) continue;
        const int l = pickLane(th);
        const int it = lnit[l]; const int base = lload[l];
        for (int j = 0; j < th; j++) {
          p_src[l][base + j] = (unsigned char)arow[pdefs[p][j]];
          if (it == 0) p_a0[l][base + j] = pdefs[p][j];
          else         p_a1[l][base + j] = pdefs[p][j];
        }
        p_dslot[l][it] = (unsigned char)(108 + p);
        p_btc[l][it] = (unsigned char)pcol_s[p];
        p_outc[l][it] = -1;
        lload[l] = (unsigned char)(base + th); lnit[l] = (unsigned char)(it + 1);
      }
      for (int c = 0; c < S; c++) {
        if ((int)ccnt[c] != th) continue;
        const int l = pickLane(th);
        const int it = lnit[l]; const int base = lload[l];
        for (int j = 0; j < th; j++) {
          p_src[l][base + j] = (unsigned char)arow[clist[c][j]];
          if (it == 0) p_a0[l][base + j] = clist[c][j];
          else         p_a1[l][base + j] = clist[c][j];
        }
        p_dslot[l][it] = (unsigned char)c;
        p_btc[l][it] = (unsigned char)c;
        p_outc[l][it] = (npcA[c] > 0) ? (short)-1 : (short)c;
        lload[l] = (unsigned char)(base + th); lnit[l] = (unsigned char)(it + 1);
      }
    }
  }
  __syncthreads();

  // ---------- phase 3: load per-lane plan into registers ----------
  int gsrc[MAXG]; float w0v[MAXG], w1v[MAXG];
#pragma unroll
  for (int e = 0; e < MAXG; e++) {
    gsrc[e] = p_src[tid][e];
    const int a0 = p_a0[tid][e], a1 = p_a1[tid][e];
    w0v[e] = (a0 >= 0) ? avalS[a0] : 0.f;
    w1v[e] = (a1 >= 0) ? avalS[a1] : 0.f;
  }
  const int d0 = p_dslot[tid][0], d1 = p_dslot[tid][1];
  const int b0c = p_btc[tid][0], b1c = p_btc[tid][1];
  const int o0 = p_outc[tid][0], o1 = p_outc[tid][1];
  const int scol = p_scol[tid];
  const float sm1 = (float)p_sm1[tid], sm2 = (float)p_sm2[tid];
  __syncthreads();

  // ---------- phase 4: forward scan (unnormalized, scaled), no in-loop x-lane --
  const int* seq = inp + (size_t)blockIdx.x * T_LEN;
  float* ob = out + (size_t)blockIdx.x * T_LEN * S;

  const int e0s = seq[0];
  {
    // initial alpha scaled to RESCALE_TARGET-magnitude territory
    const float ui0 = (d0 < 108) ? RESCALE_TARGET * pi_lds[d0] * Bt_lds[e0s * S + d0] : 0.f;
    const float ui1 = (d1 < 108) ? RESCALE_TARGET * pi_lds[d1] * Bt_lds[e0s * S + d1] : 0.f;
    alpha_lds[d0] = ui0;
    alpha_lds[d1] = ui1;
  }
  __syncthreads();
  for (int i = tid; i < S; i += 64) ob[i] = alpha_lds[i];   // row 0 (scaled; norm cancels)

  int etn = seq[1];
  for (int t = 1; t < T_LEN; t++) {
    const int ecur = etn;
    if (t + 1 < T_LEN) etn = seq[t + 1];
    const float bt0 = Bt_lds[ecur * S + b0c];   // issue early, overlaps gathers
    const float bt1 = Bt_lds[ecur * S + b1c];
    float x[MAXG];
#pragma unroll
    for (int e = 0; e < MAXG; e++) x[e] = alpha_lds[gsrc[e]];
    float aA = 0.f, aB = 0.f, bA = 0.f, bB = 0.f;
#pragma unroll
    for (int e = 0; e < MAXG; e += 2) {
      aA += x[e] * w0v[e];     aB += x[e + 1] * w0v[e + 1];
      bA += x[e] * w1v[e];     bB += x[e + 1] * w1v[e + 1];
    }
    float u0 = (aA + aB) * bt0;
    float u1 = (bA + bB) * bt1;
    const float sumv = x[0] + sm1 * x[1] + sm2 * x[2];   // full split-col value (row t-1)

    // anti-denormal flush: nothing in (0, 1e-30) ever enters alpha_lds
    u0 = (u0 >= FLUSH_EPS) ? u0 : 0.f;
    u1 = (u1 >= FLUSH_EPS) ? u1 : 0.f;

    if ((t & 15) == 15) {                  // periodic wave-uniform rescale to 1e24
      float m = fmaxf(u0, u1);
#pragma unroll
      for (int msk = 1; msk < 64; msk <<= 1) m = fmaxf(m, __shfl_xor(m, msk, 64));
      const float r = RESCALE_TARGET / m;
      u0 *= r; u1 *= r;
    }

    alpha_lds[d0] = u0;
    alpha_lds[d1] = u1;
    if (o0 >= 0) ob[(size_t)t * S + o0] = u0;
    if (o1 >= 0) ob[(size_t)t * S + o1] = u1;
    if (scol >= 0) ob[(size_t)(t - 1) * S + scol] = sumv;
  }
  // epilogue: last row's split-col values
  if (scol >= 0) {
    const float x0 = alpha_lds[gsrc[0]];
    const float x1 = alpha_lds[gsrc[1]];
    const float x2 = alpha_lds[gsrc[2]];
    ob[(size_t)(T_LEN - 1) * S + scol] = x0 + sm1 * x1 + sm2 * x2;
  }
}

// ---------- kernel 2: per-row normalization, fully parallel, BW-bound ----------
__global__ __launch_bounds__(256, 8) void hmm_norm_kernel(float* __restrict__ out,
                                                          int nrows) {
  const int wid = (int)((blockIdx.x * 256u + threadIdx.x) >> 6);  // one wave per row
  const int l = threadIdx.x & 63;
  if (wid >= nrows) return;
  float* row = out + (size_t)wid * S;
  float2 x = make_float2(0.f, 0.f);
  if (l < 54) x = *(const float2*)&row[2 * l];
  float s = x.x + x.y;
#pragma unroll
  for (int msk = 1; msk < 64; msk <<= 1) s += __shfl_xor(s, msk, 64);
  const float inv = 1.f / s;
  if (l < 54) *(float2*)&row[2 * l] = make_float2(x.x * inv, x.y * inv);
}

extern "C" void kernel_launch(void* const* d_in, const int* in_sizes, int n_in,
                              void* d_out, int out_size, void* d_ws, size_t ws_size,
                              hipStream_t stream) {
  const int* inp = (const int*)d_in[0];
  const float* w = (const float*)d_in[1];
  const float* ek = (const float*)d_in[2];
  const float* ik = (const float*)d_in[3];
  float* out = (float*)d_out;
  (void)d_ws; (void)ws_size; (void)in_sizes; (void)n_in; (void)out_size;
  hmm_scan_kernel<<<N_BATCH, 64, 0, stream>>>(inp, w, ek, ik, out);
  const int nrows = N_BATCH * T_LEN;
  hmm_norm_kernel<<<nrows / 4, 256, 0, stream>>>(out, nrows);
}

// Round 9
// 640.928 us; speedup vs baseline: 4.0510x; 1.4616x over previous
//
#include <hip/hip_runtime.h>
#include <cstdint>
#include <cstddef>

#define S 108
#define NEMIT 126
#define T_LEN 2048
#define N_BATCH 256
#define MAXG 12    // max gather entries per lane after balancing
#define MAXNE 6500 // emission nnz upper bound (actual 6432)
#define NE_A 280   // A-matrix nnz

#define RESCALE_TARGET 1e24f
#define FLUSH_EPS 1e-30f

// ================= compile-time emission structure =================
struct EmTab {
  short row[MAXNE];
  short col[MAXNE];
  short widx[MAXNE];
  int rp[S + 1];
  int n;
  int nw;
};

constexpr int cmask(int sym, int add4) {
  int m = (sym == 4) ? 0xF : (1 << sym);
  if (add4) m |= 0x10;
  return m;
}

constexpr EmTab buildEm() {
  EmTab E{};
  int n = 0, k = 0;
  auto doCall = [&](int stt, int s0_, int s1_, int s2_, int xm_, int tr_) {
    const int m0 = cmask(s0_, xm_ < 2 ? 1 : 0);
    const int m1 = cmask(s1_, xm_ < 1 ? 1 : 0);
    const int m2 = cmask(s2_, 0);
    for (int x0 = 0; x0 < 5; x0++) {
      if (!((m0 >> x0) & 1)) continue;
      for (int x1 = 0; x1 < 5; x1++) {
        if (!((m1 >> x1) & 1)) continue;
        if (x0 != 4 && x1 == 4) continue;
        for (int x2 = 0; x2 < 5; x2++) {
          if (!((m2 >> x2) & 1)) continue;
          E.row[n] = (short)stt;
          E.col[n] = (short)(x0 * 25 + x1 * 5 + x2);
          E.widx[n] = (short)(tr_ ? k++ : -1);
          n++;
        }
      }
    }
  };
  doCall(0, 4, 4, 4, 0, 1);
  doCall(1, 4, 4, 0, 0, 1);
  doCall(2, 4, 0, 3, 0, 1);
  doCall(3, 0, 3, 2, 2, 0);
  doCall(4, 3, 2, 4, 2, 1);
  doCall(5, 2, 4, 4, 2, 1);
  for (int s = 6; s <= 51; s++) doCall(s, 4, 4, 4, 2, 1);
  doCall(52, 4, 4, 3, 2, 1);
  doCall(53, 4, 3, 0, 2, 1);
  doCall(53, 4, 3, 2, 2, 1);
  doCall(54, 3, 0, 0, 2, 0);
  doCall(54, 3, 0, 2, 2, 0);
  doCall(54, 3, 2, 0, 2, 0);
  doCall(55, 4, 4, 4, 2, 1);
  for (int s = 56; s <= 106; s++) doCall(s, 4, 4, 4, 2, 1);
  E.row[n] = 107; E.col[n] = 125; E.widx[n] = -1; n++;
  E.n = n; E.nw = k;
  for (int r = 0; r <= S; r++) E.rp[r] = 0;
  for (int e = 0; e < n; e++) E.rp[E.row[e] + 1]++;
  for (int r = 0; r < S; r++) E.rp[r + 1] += E.rp[r];
  return E;
}

constexpr EmTab EM_HOST = buildEm();
static_assert(EM_HOST.n <= MAXNE && EM_HOST.n > 6000, "emission count sanity");
__device__ const EmTab g_em = EM_HOST;

// ================= compile-time A structure + full gather plan =================
// Value descriptor codes: 0 -> 1.0 ; 1 -> w[wi] ; 2 -> 1-w[wi] ;
//                         3 -> 1 - sign(w[52])^(wi odd) * |w[52]|^wi
struct APlan {
  short vcode[NE_A], vwi[NE_A];     // per-entry value descriptor
  short aidx[NE_A];                 // entry indices sorted by row
  short arp[S + 1];                 // row_ptr into aidx
  // per-lane plan (exact transcription of the R5 runtime planner)
  unsigned char src[64][MAXG];
  short a0[64][MAXG], a1[64][MAXG];
  unsigned char d0[64], d1[64], b0[64], b1[64];
  short o0[64], o1[64], scol[64];
  unsigned char sm1[64], sm2[64];
  int maxload, ncons, np;
};

constexpr APlan buildPlan() {
  APlan P{};
  short arow[NE_A] = {}, acol[NE_A] = {};
  int ne = 0;
  auto AD = [&](int r, int c, int code, int wi) {
    arow[ne] = (short)r; acol[ne] = (short)c;
    P.vcode[ne] = (short)code; P.vwi[ne] = (short)wi; ne++;
  };
  AD(0, 0, 2, 0); AD(0, 1, 1, 0); AD(1, 2, 0, 0); AD(2, 3, 0, 0);
  for (int i = 0; i < 16; i++) AD(3 + 3 * i, 4 + 3 * i, 1, 1 + i);
  for (int i = 0; i < 16; i++) AD(4 + 3 * i, 5 + 3 * i, 0, 0);
  for (int i = 0; i < 16; i++) AD(5 + 3 * i, 6 + 3 * i, 0, 0);
  for (int i = 0; i <= 16; i++) AD(3 + 3 * i, 56 + 3 * i, 1, 17 + i);
  AD(51, 52, 1, 34);
  for (int i = 0; i <= 16; i++) AD(56 + 3 * i, 57 + 3 * i, 0, 0);
  for (int i = 0; i <= 16; i++) AD(57 + 3 * i, 58 + 3 * i, 0, 0);
  for (int i = 0; i <= 16; i++) AD(58 + 3 * i, 4 + 3 * i, 1, 35 + i);
  for (int i = 0; i <= 16; i++) AD(58 + 3 * i, 56 + 3 * i, 2, 35 + i);
  for (int a = 0; a < 16; a++)
    for (int jj = a + 1; jj <= 16; jj++) AD(3 + 3 * a, 4 + 3 * jj, 3, jj - a + 1);
  AD(52, 53, 0, 0); AD(53, 54, 0, 0); AD(54, 55, 0, 0);
  AD(55, 55, 0, 0); AD(55, 107, 0, 0); AD(107, 107, 0, 0);
  // ne == 280

  // row-sorted CSR for the A row-softmax
  int rc[S + 1] = {};
  for (int e = 0; e < ne; e++) rc[arow[e] + 1]++;
  for (int r = 0; r < S; r++) rc[r + 1] += rc[r];
  for (int r = 0; r <= S; r++) P.arp[r] = (short)rc[r];
  int fill[S] = {};
  for (int e = 0; e < ne; e++) { const int r = arow[e]; P.aidx[rc[r] + fill[r]] = (short)e; fill[r]++; }

  // ---- planner (exact transcription of the R5 runtime planner) ----
  int ccnt[S] = {}; short clist[S][18] = {};
  for (int e = 0; e < ne; e++) { const int c = acol[e]; clist[c][ccnt[c]] = (short)e; ccnt[c]++; }
  int npcA[S] = {};
  short pdefs[16][6] = {}; int pcnt[16] = {}; short pcol[16] = {};
  int np = 0;
  for (int c = 0; c < S; c++) {
    while (ccnt[c] > 8) {
      const int base = ccnt[c] - 6;
      for (int j = 0; j < 6; j++) pdefs[np][j] = clist[c][base + j];
      pcnt[np] = 6; pcol[np] = (short)c;
      npcA[c]++; ccnt[c] -= 6; np++;
    }
  }
  int lload[64] = {}, lnit[64] = {};
  for (int l = 0; l < 64; l++) {
    for (int e = 0; e < MAXG; e++) { P.src[l][e] = 0; P.a0[l][e] = -1; P.a1[l][e] = -1; }
    P.d0[l] = 127; P.d1[l] = 127; P.b0[l] = 0; P.b1[l] = 0;
    P.o0[l] = -1; P.o1[l] = -1; P.scol[l] = -1; P.sm1[l] = 0; P.sm2[l] = 0;
  }
  int ncons = 0;
  for (int c = 0; c < S; c++) {
    if (ccnt[c] == 1) {
      const int e0 = clist[c][0];
      const int r = arow[e0];
      if (npcA[r] > 0) {
        const int l = 54 + ncons; ncons++;
        int k = 0;
        P.src[l][k] = (unsigned char)r; P.a0[l][k] = (short)e0; k++;
        for (int p = 0; p < np; p++)
          if (pcol[p] == r) { P.src[l][k] = (unsigned char)(108 + p); P.a0[l][k] = (short)e0; k++; }
        P.d0[l] = (unsigned char)c; P.b0[l] = (unsigned char)c; P.o0[l] = (short)c;
        P.scol[l] = (short)r;
        P.sm1[l] = (k >= 2) ? 1 : 0; P.sm2[l] = (k >= 3) ? 1 : 0;
        lload[l] = k; lnit[l] = 1;
        ccnt[c] = 0;
      }
    }
  }
  int rr = 0;
  auto pickLane = [&](int L) {
    for (;;) {
      const int pos = rr & 127; rr++;
      const int l = (pos < 64) ? pos : (127 - pos);
      if (lnit[l] < 2 && lload[l] + L <= MAXG) return l;
    }
  };
  for (int th = 8; th >= 1; th--) {
    for (int p = 0; p < np; p++) {
      if (pcnt[p] != th) continue;
      const int l = pickLane(th);
      const int it = lnit[l], base = lload[l];
      for (int j = 0; j < th; j++) {
        P.src[l][base + j] = (unsigned char)arow[pdefs[p][j]];
        if (it == 0) P.a0[l][base + j] = pdefs[p][j];
        else         P.a1[l][base + j] = pdefs[p][j];
      }
      if (it == 0) { P.d0[l] = (unsigned char)(108 + p); P.b0[l] = (unsigned char)pcol[p]; P.o0[l] = -1; }
      else         { P.d1[l] = (unsigned char)(108 + p); P.b1[l] = (unsigned char)pcol[p]; P.o1[l] = -1; }
      lload[l] = base + th; lnit[l] = it + 1;
    }
    for (int c = 0; c < S; c++) {
      if (ccnt[c] != th) continue;
      const int l = pickLane(th);
      const int it = lnit[l], base = lload[l];
      for (int j = 0; j < th; j++) {
        P.src[l][base + j] = (unsigned char)arow[clist[c][j]];
        if (it == 0) P.a0[l][base + j] = clist[c][j];
        else         P.a1[l][base + j] = clist[c][j];
      }
      const short oc = (npcA[c] > 0) ? (short)-1 : (short)c;
      if (it == 0) { P.d0[l] = (unsigned char)c; P.b0[l] = (unsigned char)c; P.o0[l] = oc; }
      else         { P.d1[l] = (unsigned char)c; P.b1[l] = (unsigned char)c; P.o1[l] = oc; }
      lload[l] = base + th; lnit[l] = it + 1;
    }
  }
  int ml = 0;
  for (int l = 0; l < 64; l++) ml = (lload[l] > ml) ? lload[l] : ml;
  P.maxload = ml; P.ncons = ncons; P.np = np;
  return P;
}

constexpr APlan PLAN_HOST = buildPlan();
static_assert(PLAN_HOST.maxload <= MAXG, "lane gather overflow");
static_assert(PLAN_HOST.ncons <= 10, "too many consumer lanes");
static_assert(PLAN_HOST.np <= 16, "too many pieces");
__device__ const APlan g_plan = PLAN_HOST;

// ================= scan kernel (probe-identical loop; constexpr plan) ==========
__global__ __launch_bounds__(64, 1) void hmm_scan_kernel(
    const int* __restrict__ inp, const float* __restrict__ w,
    const float* __restrict__ ek, const float* __restrict__ ik,
    float* __restrict__ out) {
  __shared__ __align__(16) float Bt_lds[NEMIT * S];
  __shared__ float alpha_lds[128];   // 108 states + 14 piece slots + trash(127)
  __shared__ float pi_lds[S];
  __shared__ float avalS[NE_A];

  const int tid = threadIdx.x;   // 64 threads = 1 wave

  // ---------- phase 0: zero Bt; pi softmax; A values from descriptors ----------
  for (int i = tid; i < NEMIT * S; i += 64) Bt_lds[i] = 0.f;

  {  // pi = softmax(ik)
    float q0 = ik[tid];
    float q1 = (tid + 64 < S) ? ik[tid + 64] : -1e30f;
    float mx = fmaxf(q0, q1);
#pragma unroll
    for (int msk = 1; msk < 64; msk <<= 1) mx = fmaxf(mx, __shfl_xor(mx, msk, 64));
    float e0v = expf(q0 - mx);
    float e1v = (tid + 64 < S) ? expf(q1 - mx) : 0.f;
    float zz = e0v + e1v;
#pragma unroll
    for (int msk = 1; msk < 64; msk <<= 1) zz += __shfl_xor(zz, msk, 64);
    const float rz = 1.f / zz;
    pi_lds[tid] = e0v * rz;
    if (tid + 64 < S) pi_lds[tid + 64] = e1v * rz;
  }

  {  // A values, parallel across entries
    const float wk = w[52];
    const float aw = fabsf(wk);
    const float sgnw = (wk > 0.f) ? 1.f : ((wk < 0.f) ? -1.f : 0.f);
    for (int e = tid; e < NE_A; e += 64) {
      const int code = g_plan.vcode[e];
      const int wi = g_plan.vwi[e];
      float v;
      if (code == 0) v = 1.f;
      else if (code == 1) v = w[wi];
      else if (code == 2) v = 1.f - w[wi];
      else {
        const float pw = powf(aw, (float)wi);
        v = 1.f - ((wi & 1) ? sgnw : 1.f) * pw;
      }
      avalS[e] = v;
    }
  }
  __syncthreads();

  // ---------- phase 1: A row-softmax via constexpr CSR ----------
#pragma unroll
  for (int rr = 0; rr < 2; rr++) {
    const int s = tid + rr * 64;
    if (s < S) {
      const int b = g_plan.arp[s], e2 = g_plan.arp[s + 1];
      float m = -1e30f;
      for (int j = b; j < e2; j++) m = fmaxf(m, avalS[g_plan.aidx[j]]);
      float z = 0.f;
      for (int j = b; j < e2; j++) z += expf(avalS[g_plan.aidx[j]] - m);
      const float rz = 1.f / z;
      for (int j = b; j < e2; j++) {
        const int ii = g_plan.aidx[j];
        avalS[ii] = expf(avalS[ii] - m) * rz;
      }
    }
  }
  __syncthreads();

  // ---------- phase 2: B row-softmax -> Bt_lds ----------
#pragma unroll
  for (int rr = 0; rr < 2; rr++) {
    const int r = tid + rr * 64;
    if (r < S) {
      const int b = g_em.rp[r], e2 = g_em.rp[r + 1];
      float m = -1e30f;
      for (int e = b; e < e2; e++) {
        const int wi = g_em.widx[e];
        m = fmaxf(m, (wi >= 0) ? ek[wi] : 1.f);
      }
      float z = 0.f;
      for (int e = b; e < e2; e++) {
        const int wi = g_em.widx[e];
        z += expf(((wi >= 0) ? ek[wi] : 1.f) - m);
      }
      const float rz = 1.f / z;
      for (int e = b; e < e2; e++) {
        const int wi = g_em.widx[e];
        Bt_lds[(int)g_em.col[e] * S + r] = expf(((wi >= 0) ? ek[wi] : 1.f) - m) * rz;
      }
    }
  }

  // ---------- phase 3: plan -> registers (weights from softmaxed avalS) --------
  int gsrc[MAXG]; float w0v[MAXG], w1v[MAXG];
#pragma unroll
  for (int e = 0; e < MAXG; e++) {
    gsrc[e] = g_plan.src[tid][e];
    const int a0 = g_plan.a0[tid][e], a1 = g_plan.a1[tid][e];
    w0v[e] = (a0 >= 0) ? avalS[a0] : 0.f;
    w1v[e] = (a1 >= 0) ? avalS[a1] : 0.f;
  }
  const int d0 = g_plan.d0[tid], d1 = g_plan.d1[tid];
  const int b0c = g_plan.b0[tid], b1c = g_plan.b1[tid];
  const int o0 = g_plan.o0[tid], o1 = g_plan.o1[tid];
  const int scol = g_plan.scol[tid];
  const float sm1 = (float)g_plan.sm1[tid], sm2 = (float)g_plan.sm2[tid];
  __syncthreads();   // Bt_lds final

  // ---------- phase 4: forward scan (probe-identical body) ----------
  const int* seq = inp + (size_t)blockIdx.x * T_LEN;
  float* ob = out + (size_t)blockIdx.x * T_LEN * S;

  const int e0s = seq[0];
  {
    const float ui0 = (d0 < 108) ? RESCALE_TARGET * pi_lds[d0] * Bt_lds[e0s * S + d0] : 0.f;
    const float ui1 = (d1 < 108) ? RESCALE_TARGET * pi_lds[d1] * Bt_lds[e0s * S + d1] : 0.f;
    alpha_lds[d0] = ui0;
    alpha_lds[d1] = ui1;
  }
  __syncthreads();
  for (int i = tid; i < S; i += 64) ob[i] = alpha_lds[i];   // row 0 (scaled)

  int etn = seq[1];
  for (int t = 1; t < T_LEN; t++) {
    const int ecur = etn;
    const int tn = (t + 1 < T_LEN) ? (t + 1) : (T_LEN - 1);
    etn = seq[tn];                              // unconditional uniform prefetch
    const float bt0 = Bt_lds[ecur * S + b0c];
    const float bt1 = Bt_lds[ecur * S + b1c];
    float x[MAXG];
#pragma unroll
    for (int e = 0; e < MAXG; e++) x[e] = alpha_lds[gsrc[e]];
    float aA = 0.f, aB = 0.f, bA = 0.f, bB = 0.f;
#pragma unroll
    for (int e = 0; e < MAXG; e += 2) {
      aA += x[e] * w0v[e];     aB += x[e + 1] * w0v[e + 1];
      bA += x[e] * w1v[e];     bB += x[e + 1] * w1v[e + 1];
    }
    float u0 = (aA + aB) * bt0;
    float u1 = (bA + bB) * bt1;
    const float sumv = x[0] + sm1 * x[1] + sm2 * x[2];

    u0 = (u0 >= FLUSH_EPS) ? u0 : 0.f;          // anti-denormal flush (neutral cost)
    u1 = (u1 >= FLUSH_EPS) ? u1 : 0.f;

    if ((t & 15) == 15) {                       // periodic wave-uniform rescale
      float m = fmaxf(u0, u1);
#pragma unroll
      for (int msk = 1; msk < 64; msk <<= 1) m = fmaxf(m, __shfl_xor(m, msk, 64));
      const float r = RESCALE_TARGET / m;
      u0 *= r; u1 *= r;
    }

    alpha_lds[d0] = u0;
    alpha_lds[d1] = u1;
    if (o0 >= 0) ob[(size_t)t * S + o0] = u0;
    if (o1 >= 0) ob[(size_t)t * S + o1] = u1;
    if (scol >= 0) ob[(size_t)(t - 1) * S + scol] = sumv;
  }
  // epilogue: last row's reconstructed split-column values
  if (scol >= 0) {
    const float x0 = alpha_lds[gsrc[0]];
    const float x1 = alpha_lds[gsrc[1]];
    const float x2 = alpha_lds[gsrc[2]];
    ob[(size_t)(T_LEN - 1) * S + scol] = x0 + sm1 * x1 + sm2 * x2;
  }
}

// ---------- kernel 2: per-row normalization, fully parallel, BW-bound ----------
__global__ __launch_bounds__(256, 8) void hmm_norm_kernel(float* __restrict__ out,
                                                          int nrows) {
  const int wid = (int)((blockIdx.x * 256u + threadIdx.x) >> 6);  // one wave per row
  const int l = threadIdx.x & 63;
  if (wid >= nrows) return;
  float* row = out + (size_t)wid * S;
  float2 x = make_float2(0.f, 0.f);
  if (l < 54) x = *(const float2*)&row[2 * l];
  float s = x.x + x.y;
#pragma unroll
  for (int msk = 1; msk < 64; msk <<= 1) s += __shfl_xor(s, msk, 64);
  const float inv = 1.f / s;
  if (l < 54) *(float2*)&row[2 * l] = make_float2(x.x * inv, x.y * inv);
}

extern "C" void kernel_launch(void* const* d_in, const int* in_sizes, int n_in,
                              void* d_out, int out_size, void* d_ws, size_t ws_size,
                              hipStream_t stream) {
  const int* inp = (const int*)d_in[0];
  const float* w = (const float*)d_in[1];
  const float* ek = (const float*)d_in[2];
  const float* ik = (const float*)d_in[3];
  float* out = (float*)d_out;
  (void)d_ws; (void)ws_size; (void)in_sizes; (void)n_in; (void)out_size;
  hmm_scan_kernel<<<N_BATCH, 64, 0, stream>>>(inp, w, ek, ik, out);
  const int nrows = N_BATCH * T_LEN;
  hmm_norm_kernel<<<nrows / 4, 256, 0, stream>>>(out, nrows);
}

// Round 10
// 604.732 us; speedup vs baseline: 4.2935x; 1.0599x over previous
//
#include <hip/hip_runtime.h>
#include <cstdint>
#include <cstddef>

#define S 108
#define NEMIT 126
#define T_LEN 2048
#define N_BATCH 256
#define MAXG 12    // max gather entries per lane after balancing
#define MAXNE 6500 // emission nnz upper bound (actual 6432)
#define NE_A 280   // A-matrix nnz

#define RESCALE_TARGET 1e24f
#define FLUSH_EPS 1e-30f

// ================= compile-time emission structure =================
struct EmTab {
  short row[MAXNE];
  short col[MAXNE];
  short widx[MAXNE];
  int rp[S + 1];
  int n;
  int nw;
};

constexpr int cmask(int sym, int add4) {
  int m = (sym == 4) ? 0xF : (1 << sym);
  if (add4) m |= 0x10;
  return m;
}

constexpr EmTab buildEm() {
  EmTab E{};
  int n = 0, k = 0;
  auto doCall = [&](int stt, int s0_, int s1_, int s2_, int xm_, int tr_) {
    const int m0 = cmask(s0_, xm_ < 2 ? 1 : 0);
    const int m1 = cmask(s1_, xm_ < 1 ? 1 : 0);
    const int m2 = cmask(s2_, 0);
    for (int x0 = 0; x0 < 5; x0++) {
      if (!((m0 >> x0) & 1)) continue;
      for (int x1 = 0; x1 < 5; x1++) {
        if (!((m1 >> x1) & 1)) continue;
        if (x0 != 4 && x1 == 4) continue;
        for (int x2 = 0; x2 < 5; x2++) {
          if (!((m2 >> x2) & 1)) continue;
          E.row[n] = (short)stt;
          E.col[n] = (short)(x0 * 25 + x1 * 5 + x2);
          E.widx[n] = (short)(tr_ ? k++ : -1);
          n++;
        }
      }
    }
  };
  doCall(0, 4, 4, 4, 0, 1);
  doCall(1, 4, 4, 0, 0, 1);
  doCall(2, 4, 0, 3, 0, 1);
  doCall(3, 0, 3, 2, 2, 0);
  doCall(4, 3, 2, 4, 2, 1);
  doCall(5, 2, 4, 4, 2, 1);
  for (int s = 6; s <= 51; s++) doCall(s, 4, 4, 4, 2, 1);
  doCall(52, 4, 4, 3, 2, 1);
  doCall(53, 4, 3, 0, 2, 1);
  doCall(53, 4, 3, 2, 2, 1);
  doCall(54, 3, 0, 0, 2, 0);
  doCall(54, 3, 0, 2, 2, 0);
  doCall(54, 3, 2, 0, 2, 0);
  doCall(55, 4, 4, 4, 2, 1);
  for (int s = 56; s <= 106; s++) doCall(s, 4, 4, 4, 2, 1);
  E.row[n] = 107; E.col[n] = 125; E.widx[n] = -1; n++;
  E.n = n; E.nw = k;
  for (int r = 0; r <= S; r++) E.rp[r] = 0;
  for (int e = 0; e < n; e++) E.rp[E.row[e] + 1]++;
  for (int r = 0; r < S; r++) E.rp[r + 1] += E.rp[r];
  return E;
}

constexpr EmTab EM_HOST = buildEm();
static_assert(EM_HOST.n <= MAXNE && EM_HOST.n > 6000, "emission count sanity");
__device__ const EmTab g_em = EM_HOST;

// ================= compile-time A structure + full gather plan =================
struct APlan {
  short vcode[NE_A], vwi[NE_A];
  short aidx[NE_A];
  short arp[S + 1];
  unsigned char src[64][MAXG];
  short a0[64][MAXG], a1[64][MAXG];
  unsigned char d0[64], d1[64], b0[64], b1[64];
  short o0[64], o1[64], scol[64];
  unsigned char sm1[64], sm2[64];
  int maxload, ncons, np;
};

constexpr APlan buildPlan() {
  APlan P{};
  short arow[NE_A] = {}, acol[NE_A] = {};
  int ne = 0;
  auto AD = [&](int r, int c, int code, int wi) {
    arow[ne] = (short)r; acol[ne] = (short)c;
    P.vcode[ne] = (short)code; P.vwi[ne] = (short)wi; ne++;
  };
  AD(0, 0, 2, 0); AD(0, 1, 1, 0); AD(1, 2, 0, 0); AD(2, 3, 0, 0);
  for (int i = 0; i < 16; i++) AD(3 + 3 * i, 4 + 3 * i, 1, 1 + i);
  for (int i = 0; i < 16; i++) AD(4 + 3 * i, 5 + 3 * i, 0, 0);
  for (int i = 0; i < 16; i++) AD(5 + 3 * i, 6 + 3 * i, 0, 0);
  for (int i = 0; i <= 16; i++) AD(3 + 3 * i, 56 + 3 * i, 1, 17 + i);
  AD(51, 52, 1, 34);
  for (int i = 0; i <= 16; i++) AD(56 + 3 * i, 57 + 3 * i, 0, 0);
  for (int i = 0; i <= 16; i++) AD(57 + 3 * i, 58 + 3 * i, 0, 0);
  for (int i = 0; i <= 16; i++) AD(58 + 3 * i, 4 + 3 * i, 1, 35 + i);
  for (int i = 0; i <= 16; i++) AD(58 + 3 * i, 56 + 3 * i, 2, 35 + i);
  for (int a = 0; a < 16; a++)
    for (int jj = a + 1; jj <= 16; jj++) AD(3 + 3 * a, 4 + 3 * jj, 3, jj - a + 1);
  AD(52, 53, 0, 0); AD(53, 54, 0, 0); AD(54, 55, 0, 0);
  AD(55, 55, 0, 0); AD(55, 107, 0, 0); AD(107, 107, 0, 0);

  int rc[S + 1] = {};
  for (int e = 0; e < ne; e++) rc[arow[e] + 1]++;
  for (int r = 0; r < S; r++) rc[r + 1] += rc[r];
  for (int r = 0; r <= S; r++) P.arp[r] = (short)rc[r];
  int fill[S] = {};
  for (int e = 0; e < ne; e++) { const int r = arow[e]; P.aidx[rc[r] + fill[r]] = (short)e; fill[r]++; }

  int ccnt[S] = {}; short clist[S][18] = {};
  for (int e = 0; e < ne; e++) { const int c = acol[e]; clist[c][ccnt[c]] = (short)e; ccnt[c]++; }
  int npcA[S] = {};
  short pdefs[16][6] = {}; int pcnt[16] = {}; short pcol[16] = {};
  int np = 0;
  for (int c = 0; c < S; c++) {
    while (ccnt[c] > 8) {
      const int base = ccnt[c] - 6;
      for (int j = 0; j < 6; j++) pdefs[np][j] = clist[c][base + j];
      pcnt[np] = 6; pcol[np] = (short)c;
      npcA[c]++; ccnt[c] -= 6; np++;
    }
  }
  int lload[64] = {}, lnit[64] = {};
  for (int l = 0; l < 64; l++) {
    for (int e = 0; e < MAXG; e++) { P.src[l][e] = 0; P.a0[l][e] = -1; P.a1[l][e] = -1; }
    P.d0[l] = 127; P.d1[l] = 127; P.b0[l] = 0; P.b1[l] = 0;
    P.o0[l] = -1; P.o1[l] = -1; P.scol[l] = -1; P.sm1[l] = 0; P.sm2[l] = 0;
  }
  int ncons = 0;
  for (int c = 0; c < S; c++) {
    if (ccnt[c] == 1) {
      const int e0 = clist[c][0];
      const int r = arow[e0];
      if (npcA[r] > 0) {
        const int l = 54 + ncons; ncons++;
        int k = 0;
        P.src[l][k] = (unsigned char)r; P.a0[l][k] = (short)e0; k++;
        for (int p = 0; p < np; p++)
          if (pcol[p] == r) { P.src[l][k] = (unsigned char)(108 + p); P.a0[l][k] = (short)e0; k++; }
        P.d0[l] = (unsigned char)c; P.b0[l] = (unsigned char)c; P.o0[l] = (short)c;
        P.scol[l] = (short)r;
        P.sm1[l] = (k >= 2) ? 1 : 0; P.sm2[l] = (k >= 3) ? 1 : 0;
        lload[l] = k; lnit[l] = 1;
        ccnt[c] = 0;
      }
    }
  }
  int rr = 0;
  auto pickLane = [&](int L) {
    for (;;) {
      const int pos = rr & 127; rr++;
      const int l = (pos < 64) ? pos : (127 - pos);
      if (lnit[l] < 2 && lload[l] + L <= MAXG) return l;
    }
  };
  for (int th = 8; th >= 1; th--) {
    for (int p = 0; p < np; p++) {
      if (pcnt[p] != th) continue;
      const int l = pickLane(th);
      const int it = lnit[l], base = lload[l];
      for (int j = 0; j < th; j++) {
        P.src[l][base + j] = (unsigned char)arow[pdefs[p][j]];
        if (it == 0) P.a0[l][base + j] = pdefs[p][j];
        else         P.a1[l][base + j] = pdefs[p][j];
      }
      if (it == 0) { P.d0[l] = (unsigned char)(108 + p); P.b0[l] = (unsigned char)pcol[p]; P.o0[l] = -1; }
      else         { P.d1[l] = (unsigned char)(108 + p); P.b1[l] = (unsigned char)pcol[p]; P.o1[l] = -1; }
      lload[l] = base + th; lnit[l] = it + 1;
    }
    for (int c = 0; c < S; c++) {
      if (ccnt[c] != th) continue;
      const int l = pickLane(th);
      const int it = lnit[l], base = lload[l];
      for (int j = 0; j < th; j++) {
        P.src[l][base + j] = (unsigned char)arow[clist[c][j]];
        if (it == 0) P.a0[l][base + j] = clist[c][j];
        else         P.a1[l][base + j] = clist[c][j];
      }
      const short oc = (npcA[c] > 0) ? (short)-1 : (short)c;
      if (it == 0) { P.d0[l] = (unsigned char)c; P.b0[l] = (unsigned char)c; P.o0[l] = oc; }
      else         { P.d1[l] = (unsigned char)c; P.b1[l] = (unsigned char)c; P.o1[l] = oc; }
      lload[l] = base + th; lnit[l] = it + 1;
    }
  }
  int ml = 0;
  for (int l = 0; l < 64; l++) ml = (lload[l] > ml) ? lload[l] : ml;
  P.maxload = ml; P.ncons = ncons; P.np = np;
  return P;
}

constexpr APlan PLAN_HOST = buildPlan();
static_assert(PLAN_HOST.maxload <= MAXG, "lane gather overflow");
static_assert(PLAN_HOST.ncons <= 10, "too many consumer lanes");
static_assert(PLAN_HOST.np <= 16, "too many pieces");
__device__ const APlan g_plan = PLAN_HOST;

// ================= scan kernel: producer wave + consumer wave =================
__global__ __launch_bounds__(128, 1) void hmm_scan_kernel(
    const int* __restrict__ inp, const float* __restrict__ w,
    const float* __restrict__ ek, const float* __restrict__ ik,
    float* __restrict__ out) {
  __shared__ __align__(16) float Bt_lds[NEMIT * S];
  __shared__ __align__(16) float ring[32 * S];   // 32-row output ring (2 halves)
  __shared__ float alpha_lds[128];               // 108 states + piece slots + trash
  __shared__ float pi_lds[S];
  __shared__ float avalS[NE_A];
  __shared__ __align__(16) int seq_lds[T_LEN];   // whole symbol sequence (8 KB)

  const int tid = threadIdx.x;
  const int lid = tid & 63;
  const int wv = tid >> 6;   // 0 = producer, 1 = consumer

  // ---------- setup (both waves cooperate) ----------
  for (int i = tid; i < NEMIT * S; i += 128) Bt_lds[i] = 0.f;

  {  // seq -> LDS (int4 loads)
    const int4* s4 = (const int4*)(inp + (size_t)blockIdx.x * T_LEN);
    int4* d4 = (int4*)seq_lds;
    for (int i = tid; i < T_LEN / 4; i += 128) d4[i] = s4[i];
  }

  if (wv == 0) {  // pi = softmax(ik), single wave (shfl)
    float q0 = ik[lid];
    float q1 = (lid + 64 < S) ? ik[lid + 64] : -1e30f;
    float mx = fmaxf(q0, q1);
#pragma unroll
    for (int msk = 1; msk < 64; msk <<= 1) mx = fmaxf(mx, __shfl_xor(mx, msk, 64));
    float e0v = expf(q0 - mx);
    float e1v = (lid + 64 < S) ? expf(q1 - mx) : 0.f;
    float zz = e0v + e1v;
#pragma unroll
    for (int msk = 1; msk < 64; msk <<= 1) zz += __shfl_xor(zz, msk, 64);
    const float rz = 1.f / zz;
    pi_lds[lid] = e0v * rz;
    if (lid + 64 < S) pi_lds[lid + 64] = e1v * rz;
  }

  {  // A values from descriptors, parallel across 128 threads
    const float wk = w[52];
    const float aw = fabsf(wk);
    const float sgnw = (wk > 0.f) ? 1.f : ((wk < 0.f) ? -1.f : 0.f);
    for (int e = tid; e < NE_A; e += 128) {
      const int code = g_plan.vcode[e];
      const int wi = g_plan.vwi[e];
      float v;
      if (code == 0) v = 1.f;
      else if (code == 1) v = w[wi];
      else if (code == 2) v = 1.f - w[wi];
      else {
        const float pw = powf(aw, (float)wi);
        v = 1.f - ((wi & 1) ? sgnw : 1.f) * pw;
      }
      avalS[e] = v;
    }
  }
  __syncthreads();

  // A row-softmax (one row per thread, 108 < 128)
  if (tid < S) {
    const int b = g_plan.arp[tid], e2 = g_plan.arp[tid + 1];
    float m = -1e30f;
    for (int j = b; j < e2; j++) m = fmaxf(m, avalS[g_plan.aidx[j]]);
    float z = 0.f;
    for (int j = b; j < e2; j++) z += expf(avalS[g_plan.aidx[j]] - m);
    const float rz = 1.f / z;
    for (int j = b; j < e2; j++) {
      const int ii = g_plan.aidx[j];
      avalS[ii] = expf(avalS[ii] - m) * rz;
    }
  }
  __syncthreads();

  // B row-softmax (one row per thread)
  if (tid < S) {
    const int r = tid;
    const int b = g_em.rp[r], e2 = g_em.rp[r + 1];
    float m = -1e30f;
    for (int e = b; e < e2; e++) {
      const int wi = g_em.widx[e];
      m = fmaxf(m, (wi >= 0) ? ek[wi] : 1.f);
    }
    float z = 0.f;
    for (int e = b; e < e2; e++) {
      const int wi = g_em.widx[e];
      z += expf(((wi >= 0) ? ek[wi] : 1.f) - m);
    }
    const float rz = 1.f / z;
    for (int e = b; e < e2; e++) {
      const int wi = g_em.widx[e];
      Bt_lds[(int)g_em.col[e] * S + r] = expf(((wi >= 0) ? ek[wi] : 1.f) - m) * rz;
    }
  }

  // plan -> registers (indexed by lane; wave 1 loads too, unused)
  int gsrc[MAXG]; float w0v[MAXG], w1v[MAXG];
#pragma unroll
  for (int e = 0; e < MAXG; e++) {
    gsrc[e] = g_plan.src[lid][e];
    const int a0 = g_plan.a0[lid][e], a1 = g_plan.a1[lid][e];
    w0v[e] = (a0 >= 0) ? avalS[a0] : 0.f;
    w1v[e] = (a1 >= 0) ? avalS[a1] : 0.f;
  }
  const int d0 = g_plan.d0[lid], d1 = g_plan.d1[lid];
  const int b0c = g_plan.b0[lid], b1c = g_plan.b1[lid];
  const int o0 = g_plan.o0[lid], o1 = g_plan.o1[lid];
  const int scol = g_plan.scol[lid];
  const float sm1 = (float)g_plan.sm1[lid], sm2 = (float)g_plan.sm2[lid];
  __syncthreads();   // Bt_lds, avalS, seq_lds final

  float* ob = out + (size_t)blockIdx.x * T_LEN * S;
  int etn = 0;
  float u0 = 0.f, u1 = 0.f;

  if (wv == 0) {  // init: row 0 into alpha + ring row 0
    const int e0s = seq_lds[0];
    const float ui0 = (d0 < 108) ? RESCALE_TARGET * pi_lds[d0] * Bt_lds[e0s * S + d0] : 0.f;
    const float ui1 = (d1 < 108) ? RESCALE_TARGET * pi_lds[d1] * Bt_lds[e0s * S + d1] : 0.f;
    alpha_lds[d0] = ui0;
    alpha_lds[d1] = ui1;
    for (int i = lid; i < S; i += 64) ring[i] = alpha_lds[i];   // same-wave order OK
    etn = seq_lds[1];
  }

  // ---------- main: 128 groups of 16 steps; producer fills ring half,
  // ---------- consumer drains the other half; one barrier per group ----------
  for (int k = 0; k < 128; k++) {
    if (wv == 0) {
      const int tbeg = (k == 0) ? 1 : 16 * k;
      const int tend = 16 * k + 16;
      for (int t = tbeg; t < tend; t++) {
        const int ecur = etn;
        etn = seq_lds[(t + 1 < T_LEN) ? t + 1 : T_LEN - 1];   // LDS broadcast
        const float bt0 = Bt_lds[ecur * S + b0c];
        const float bt1 = Bt_lds[ecur * S + b1c];
        float x[MAXG];
#pragma unroll
        for (int e = 0; e < MAXG; e++) x[e] = alpha_lds[gsrc[e]];
        float aA = 0.f, aB = 0.f, bA = 0.f, bB = 0.f;
#pragma unroll
        for (int e = 0; e < MAXG; e += 2) {
          aA += x[e] * w0v[e];     aB += x[e + 1] * w0v[e + 1];
          bA += x[e] * w1v[e];     bB += x[e + 1] * w1v[e + 1];
        }
        u0 = (aA + aB) * bt0;
        u1 = (bA + bB) * bt1;
        const float sumv = x[0] + sm1 * x[1] + sm2 * x[2];

        u0 = (u0 >= FLUSH_EPS) ? u0 : 0.f;
        u1 = (u1 >= FLUSH_EPS) ? u1 : 0.f;

        if ((t & 15) == 15) {                  // last step of each group
          float m = fmaxf(u0, u1);
#pragma unroll
          for (int msk = 1; msk < 64; msk <<= 1) m = fmaxf(m, __shfl_xor(m, msk, 64));
          const float r = RESCALE_TARGET / m;
          u0 *= r; u1 *= r;
        }

        alpha_lds[d0] = u0;
        alpha_lds[d1] = u1;
        const int rs = (t & 31) * S;
        if (o0 >= 0) ring[rs + o0] = u0;       // LDS-only output staging
        if (o1 >= 0) ring[rs + o1] = u1;
        if (scol >= 0 && (t & 15) != 0) ring[((t - 1) & 31) * S + scol] = sumv;
      }
      if (scol >= 0) {  // end-of-group: split-col value for the group's last row
        const float x0 = alpha_lds[gsrc[0]];
        const float x1 = alpha_lds[gsrc[1]];
        const float x2 = alpha_lds[gsrc[2]];
        ring[((tend - 1) & 31) * S + scol] = x0 + sm1 * x1 + sm2 * x2;
      }
    } else {
      if (k > 0) {  // drain group k-1 (other ring half), coalesced float4
        const int g = k - 1;
        const float* src = &ring[(g & 1) * 16 * S];
        float* dst = ob + (size_t)g * 16 * S;
#pragma unroll
        for (int k2 = 0; k2 < 7; k2++) {
          const int idx = (k2 * 64 + lid) * 4;
          if (idx < 16 * S) *(float4*)&dst[idx] = *(const float4*)&src[idx];
        }
      }
    }
    __syncthreads();
  }
  // tail: drain group 127 (both waves)
  {
    const float* src = &ring[(127 & 1) * 16 * S];
    float* dst = ob + (size_t)127 * 16 * S;
#pragma unroll
    for (int k2 = 0; k2 < 4; k2++) {
      const int idx = (k2 * 128 + tid) * 4;
      if (idx < 16 * S) *(float4*)&dst[idx] = *(const float4*)&src[idx];
    }
  }
}

// ---------- kernel 2: per-row normalization, fully parallel, BW-bound ----------
__global__ __launch_bounds__(256, 8) void hmm_norm_kernel(float* __restrict__ out,
                                                          int nrows) {
  const int wid = (int)((blockIdx.x * 256u + threadIdx.x) >> 6);  // one wave per row
  const int l = threadIdx.x & 63;
  if (wid >= nrows) return;
  float* row = out + (size_t)wid * S;
  float2 x = make_float2(0.f, 0.f);
  if (l < 54) x = *(const float2*)&row[2 * l];
  float s = x.x + x.y;
#pragma unroll
  for (int msk = 1; msk < 64; msk <<= 1) s += __shfl_xor(s, msk, 64);
  const float inv = 1.f / s;
  if (l < 54) *(float2*)&row[2 * l] = make_float2(x.x * inv, x.y * inv);
}

extern "C" void kernel_launch(void* const* d_in, const int* in_sizes, int n_in,
                              void* d_out, int out_size, void* d_ws, size_t ws_size,
                              hipStream_t stream) {
  const int* inp = (const int*)d_in[0];
  const float* w = (const float*)d_in[1];
  const float* ek = (const float*)d_in[2];
  const float* ik = (const float*)d_in[3];
  float* out = (float*)d_out;
  (void)d_ws; (void)ws_size; (void)in_sizes; (void)n_in; (void)out_size;
  hmm_scan_kernel<<<N_BATCH, 128, 0, stream>>>(inp, w, ek, ik, out);
  const int nrows = N_BATCH * T_LEN;
  hmm_norm_kernel<<<nrows / 4, 256, 0, stream>>>(out, nrows);
}